// Round 2
// baseline (462.759 us; speedup 1.0000x reference)
//
#include <hip/hip_runtime.h>
#include <math.h>

// Problem dims (fixed by the reference)
#define BN    32          // batch
#define TN    512         // TFs
#define GN    2000        // genes
#define PPGN  10          // peaks per gene
#define PN    (GN*PPGN)   // 20000 peaks
#define EN    64000       // edges
#define NOUTN 10          // output channels
#define BGN   8           // batches per thread in k_perpeak

// Stage 1: per_peak[b,p] = sum_t x[b,t,p] * W_sub[t,p]
// Lanes take consecutive p -> coalesced 256B wave loads. Each thread keeps
// BGN batch accumulators AND software-pipelines the next t's loads so two
// t-slices of x are in flight chip-wide (2x2.56MB = 20KB/CU > 9.2KB
// BW*latency product). x is streamed once -> nontemporal; W_sub is re-read
// 4x -> cached (L3-resident at 41MB).
__global__ void k_perpeak(const float* __restrict__ x,
                          const float* __restrict__ W_sub,
                          float* __restrict__ per_peak) {
    int idx = blockIdx.x * blockDim.x + threadIdx.x;
    if (idx >= (BN / BGN) * PN) return;
    int p  = idx % PN;
    int bg = idx / PN;

    float acc[BGN];
#pragma unroll
    for (int j = 0; j < BGN; ++j) acc[j] = 0.0f;

    const float* xp = x + (size_t)bg * BGN * TN * PN + p;
    const float* wp = W_sub + p;

    float xv[BGN], xn[BGN];
    float w  = wp[0];
#pragma unroll
    for (int j = 0; j < BGN; ++j)
        xv[j] = __builtin_nontemporal_load(&xp[(size_t)j * TN * PN]);

    for (int t = 0; t < TN - 1; ++t) {
        // prefetch t+1 (issued before the dependent FMAs on t)
        float wn = wp[(size_t)(t + 1) * PN];
#pragma unroll
        for (int j = 0; j < BGN; ++j)
            xn[j] = __builtin_nontemporal_load(
                        &xp[(size_t)j * TN * PN + (size_t)(t + 1) * PN]);
#pragma unroll
        for (int j = 0; j < BGN; ++j)
            acc[j] = fmaf(xv[j], w, acc[j]);
        w = wn;
#pragma unroll
        for (int j = 0; j < BGN; ++j) xv[j] = xn[j];
    }
#pragma unroll
    for (int j = 0; j < BGN; ++j)
        acc[j] = fmaf(xv[j], w, acc[j]);

#pragma unroll
    for (int j = 0; j < BGN; ++j)
        __builtin_nontemporal_store(acc[j],
            &per_peak[(size_t)(bg * BGN + j) * PN + p]);
}

// Stage 2: h[b,g] = relu(sum_{k<10} per_peak[b, g*10+k] + b_sub[g])
__global__ void k_h(const float* __restrict__ per_peak,
                    const float* __restrict__ b_sub,
                    float* __restrict__ h) {
    int idx = blockIdx.x * blockDim.x + threadIdx.x;
    if (idx >= BN * GN) return;
    int g = idx % GN, b = idx / GN;
    const float* pp = per_peak + (size_t)b * PN + g * PPGN;
    float s = b_sub[g];
#pragma unroll
    for (int k = 0; k < PPGN; ++k) s += pp[k];
    h[idx] = fmaxf(s, 0.0f);
}

// Stage 3a: degree of target nodes (col)
__global__ void k_deg(const int* __restrict__ col, float* __restrict__ deg) {
    int e = blockIdx.x * blockDim.x + threadIdx.x;
    if (e < EN) atomicAdd(&deg[col[e]], 1.0f);
}

// Stage 3b: dinv = deg^-1/2 (0 where deg == 0)
__global__ void k_dinv(const float* __restrict__ deg, float* __restrict__ dinv) {
    int g = blockIdx.x * blockDim.x + threadIdx.x;
    if (g < GN) {
        float d = deg[g];
        dinv[g] = (d > 0.0f) ? (1.0f / sqrtf(d)) : 0.0f;
    }
}

// Stage 3c: s[b,g] = sum_{e: col[e]==g} dinv[row]*dinv[col] * h[b,row]
// (GCNConv is rank-1 in the channel dim: agg[b,g,c] = W_gcn[c]*s[b,g] + b_gcn[c])
__global__ void k_s(const int* __restrict__ row, const int* __restrict__ col,
                    const float* __restrict__ dinv, const float* __restrict__ h,
                    float* __restrict__ s) {
    int idx = blockIdx.x * blockDim.x + threadIdx.x;
    if (idx >= EN * BN) return;
    int b = idx % BN;      // lanes 0..31 share e -> broadcast row/col loads
    int e = idx / BN;
    int r = row[e], c = col[e];
    float nrm = dinv[r] * dinv[c];
    atomicAdd(&s[(size_t)b * GN + c], nrm * h[(size_t)b * GN + r]);
}

// Stage 4: out[b,n] = sum_g sum_c relu(W_gcn[c]*s[b,g]+b_gcn[c]) * W_out[n, 2g+c] + b_out[n]
// One wave (64 threads) per (b,n).
__global__ void k_out(const float* __restrict__ s,
                      const float* __restrict__ W_gcn,
                      const float* __restrict__ b_gcn,
                      const float* __restrict__ W_out,
                      const float* __restrict__ b_out,
                      float* __restrict__ out) {
    int b = blockIdx.x / NOUTN;
    int n = blockIdx.x % NOUTN;
    int lane = threadIdx.x;

    float w0 = W_gcn[0], w1 = W_gcn[1];
    float c0 = b_gcn[0], c1 = b_gcn[1];

    float acc = 0.0f;
    for (int g = lane; g < GN; g += 64) {
        float sv = s[(size_t)b * GN + g];
        float g0 = fmaxf(fmaf(sv, w0, c0), 0.0f);
        float g1 = fmaxf(fmaf(sv, w1, c1), 0.0f);
        const float* wo = &W_out[(size_t)n * (GN * 2) + 2 * g];
        acc = fmaf(g0, wo[0], acc);
        acc = fmaf(g1, wo[1], acc);
    }
#pragma unroll
    for (int off = 32; off > 0; off >>= 1)
        acc += __shfl_down(acc, off);
    if (lane == 0) out[b * NOUTN + n] = acc + b_out[n];
}

extern "C" void kernel_launch(void* const* d_in, const int* in_sizes, int n_in,
                              void* d_out, int out_size, void* d_ws, size_t ws_size,
                              hipStream_t stream) {
    const float* x         = (const float*)d_in[0];
    const int*   edge_index= (const int*)  d_in[1];
    const float* W_sub     = (const float*)d_in[2];
    const float* b_sub     = (const float*)d_in[3];
    const float* W_gcn     = (const float*)d_in[4];
    const float* b_gcn     = (const float*)d_in[5];
    const float* W_out     = (const float*)d_in[6];
    const float* b_out     = (const float*)d_in[7];
    float* out = (float*)d_out;

    char* ws = (char*)d_ws;
    float* per_peak = (float*)(ws);                 // B*P   floats = 2,560,000 B
    float* h        = (float*)(ws + 2560000);       // B*G   floats =   256,000 B
    float* deg      = (float*)(ws + 2816000);       // G     floats =     8,000 B
    float* dinv     = (float*)(ws + 2824000);       // G     floats =     8,000 B
    float* s        = (float*)(ws + 2832000);       // B*G   floats =   256,000 B

    const int* row = edge_index;        // edge_index[0,:]
    const int* col = edge_index + EN;   // edge_index[1,:]

    // zero the atomic-accumulated buffers every call (graph-capture legal)
    hipMemsetAsync(deg, 0, GN * sizeof(float), stream);
    hipMemsetAsync(s,   0, (size_t)BN * GN * sizeof(float), stream);

    k_perpeak<<<(((BN / BGN) * PN) + 255) / 256, 256, 0, stream>>>(x, W_sub, per_peak);
    k_h      <<<((BN * GN) + 255) / 256,       256, 0, stream>>>(per_peak, b_sub, h);
    k_deg    <<<(EN + 255) / 256,              256, 0, stream>>>(col, deg);
    k_dinv   <<<(GN + 255) / 256,              256, 0, stream>>>(deg, dinv);
    k_s      <<<((EN * BN) + 255) / 256,       256, 0, stream>>>(row, col, dinv, h, s);
    k_out    <<<BN * NOUTN, 64, 0, stream>>>(s, W_gcn, b_gcn, W_out, b_out, out);
}

// Round 3
// 441.541 us; speedup vs baseline: 1.0481x; 1.0481x over previous
//
#include <hip/hip_runtime.h>
#include <math.h>

// Problem dims (fixed by the reference)
#define BN    32          // batch
#define TN    512         // TFs
#define GN    2000        // genes
#define PPGN  10          // peaks per gene
#define PN    (GN*PPGN)   // 20000 peaks
#define EN    64000       // edges
#define NOUTN 10          // output channels
#define PQN   (PN/4)      // 5000 p-quads (float4 granules)

typedef float float4v __attribute__((ext_vector_type(4)));

// Stage 1: per_peak[b,p] = sum_t x[b,t,p] * W_sub[t,p]
// One thread per (b, p-quad). float4 loads: 16B/lane -> 1KB per wave-load.
// 500 blocks x 320 threads = 160,000 threads exactly (no tail, ~2 blocks/CU,
// 10 waves/CU). unroll-8 keeps ~16 x 1KB wave-loads in flight per wave
// (>=10KB/wave, far past the ~9.2KB/CU BW*latency knee that capped R1).
// x is streamed once -> nontemporal (keeps L2 for W_sub, which all 32 b-streams
// re-read in near-lockstep -> L2-resident window).
__global__ __launch_bounds__(320)
void k_perpeak(const float* __restrict__ x,
               const float* __restrict__ W_sub,
               float* __restrict__ per_peak) {
    int idx = blockIdx.x * 320 + threadIdx.x;   // [0, 160000)
    int b   = idx / PQN;
    int pq  = idx % PQN;

    const float4v* xp = (const float4v*)(x + (size_t)b * TN * PN) + pq;
    const float4v* wp = (const float4v*)W_sub + pq;

    float4v acc = {0.f, 0.f, 0.f, 0.f};
#pragma unroll 8
    for (int t = 0; t < TN; ++t) {
        float4v xv = __builtin_nontemporal_load(xp + (size_t)t * PQN);
        float4v wv = wp[(size_t)t * PQN];
        acc = xv * wv + acc;   // contracts to v_fma (ffp-contract=fast)
    }

    float4v* pp = (float4v*)(per_peak + (size_t)b * PN) + pq;
    *pp = acc;                 // cached store: k_h re-reads from L2
}

// Stage 2: h[b,g] = relu(sum_{k<10} per_peak[b, g*10+k] + b_sub[g])
__global__ void k_h(const float* __restrict__ per_peak,
                    const float* __restrict__ b_sub,
                    float* __restrict__ h) {
    int idx = blockIdx.x * blockDim.x + threadIdx.x;
    if (idx >= BN * GN) return;
    int g = idx % GN, b = idx / GN;
    const float* pp = per_peak + (size_t)b * PN + g * PPGN;
    float s = b_sub[g];
#pragma unroll
    for (int k = 0; k < PPGN; ++k) s += pp[k];
    h[idx] = fmaxf(s, 0.0f);
}

// Stage 3a: degree of target nodes (col)
__global__ void k_deg(const int* __restrict__ col, float* __restrict__ deg) {
    int e = blockIdx.x * blockDim.x + threadIdx.x;
    if (e < EN) atomicAdd(&deg[col[e]], 1.0f);
}

// Stage 3b: dinv = deg^-1/2 (0 where deg == 0)
__global__ void k_dinv(const float* __restrict__ deg, float* __restrict__ dinv) {
    int g = blockIdx.x * blockDim.x + threadIdx.x;
    if (g < GN) {
        float d = deg[g];
        dinv[g] = (d > 0.0f) ? (1.0f / sqrtf(d)) : 0.0f;
    }
}

// Stage 3c: s[b,g] = sum_{e: col[e]==g} dinv[row]*dinv[col] * h[b,row]
// (GCNConv is rank-1 in the channel dim: agg[b,g,c] = W_gcn[c]*s[b,g] + b_gcn[c])
__global__ void k_s(const int* __restrict__ row, const int* __restrict__ col,
                    const float* __restrict__ dinv, const float* __restrict__ h,
                    float* __restrict__ s) {
    int idx = blockIdx.x * blockDim.x + threadIdx.x;
    if (idx >= EN * BN) return;
    int b = idx % BN;      // lanes share e -> broadcast row/col loads
    int e = idx / BN;
    int r = row[e], c = col[e];
    float nrm = dinv[r] * dinv[c];
    atomicAdd(&s[(size_t)b * GN + c], nrm * h[(size_t)b * GN + r]);
}

// Stage 4: out[b,n] = sum_g sum_c relu(W_gcn[c]*s[b,g]+b_gcn[c]) * W_out[n,2g+c] + b_out[n]
// One wave (64 threads) per (b,n).
__global__ void k_out(const float* __restrict__ s,
                      const float* __restrict__ W_gcn,
                      const float* __restrict__ b_gcn,
                      const float* __restrict__ W_out,
                      const float* __restrict__ b_out,
                      float* __restrict__ out) {
    int b = blockIdx.x / NOUTN;
    int n = blockIdx.x % NOUTN;
    int lane = threadIdx.x;

    float w0 = W_gcn[0], w1 = W_gcn[1];
    float c0 = b_gcn[0], c1 = b_gcn[1];

    float acc = 0.0f;
    for (int g = lane; g < GN; g += 64) {
        float sv = s[(size_t)b * GN + g];
        float g0 = fmaxf(fmaf(sv, w0, c0), 0.0f);
        float g1 = fmaxf(fmaf(sv, w1, c1), 0.0f);
        const float* wo = &W_out[(size_t)n * (GN * 2) + 2 * g];
        acc = fmaf(g0, wo[0], acc);
        acc = fmaf(g1, wo[1], acc);
    }
#pragma unroll
    for (int off = 32; off > 0; off >>= 1)
        acc += __shfl_down(acc, off);
    if (lane == 0) out[b * NOUTN + n] = acc + b_out[n];
}

extern "C" void kernel_launch(void* const* d_in, const int* in_sizes, int n_in,
                              void* d_out, int out_size, void* d_ws, size_t ws_size,
                              hipStream_t stream) {
    const float* x         = (const float*)d_in[0];
    const int*   edge_index= (const int*)  d_in[1];
    const float* W_sub     = (const float*)d_in[2];
    const float* b_sub     = (const float*)d_in[3];
    const float* W_gcn     = (const float*)d_in[4];
    const float* b_gcn     = (const float*)d_in[5];
    const float* W_out     = (const float*)d_in[6];
    const float* b_out     = (const float*)d_in[7];
    float* out = (float*)d_out;

    char* ws = (char*)d_ws;
    float* per_peak = (float*)(ws);                 // B*P   floats = 2,560,000 B
    float* h        = (float*)(ws + 2560000);       // B*G   floats =   256,000 B
    float* deg      = (float*)(ws + 2816000);       // G     floats =     8,000 B
    float* dinv     = (float*)(ws + 2824000);       // G     floats =     8,000 B
    float* s        = (float*)(ws + 2832000);       // B*G   floats =   256,000 B

    const int* row = edge_index;        // edge_index[0,:]
    const int* col = edge_index + EN;   // edge_index[1,:]

    // zero the atomic-accumulated buffers every call (graph-capture legal)
    hipMemsetAsync(deg, 0, GN * sizeof(float), stream);
    hipMemsetAsync(s,   0, (size_t)BN * GN * sizeof(float), stream);

    k_perpeak<<<500, 320, 0, stream>>>(x, W_sub, per_peak);
    k_h      <<<((BN * GN) + 255) / 256, 256, 0, stream>>>(per_peak, b_sub, h);
    k_deg    <<<(EN + 255) / 256,        256, 0, stream>>>(col, deg);
    k_dinv   <<<(GN + 255) / 256,        256, 0, stream>>>(deg, dinv);
    k_s      <<<((EN * BN) + 255) / 256, 256, 0, stream>>>(row, col, dinv, h, s);
    k_out    <<<BN * NOUTN, 64, 0, stream>>>(s, W_gcn, b_gcn, W_out, b_out, out);
}

// Round 4
// 360.467 us; speedup vs baseline: 1.2838x; 1.2249x over previous
//
#include <hip/hip_runtime.h>
#include <math.h>

// Problem dims (fixed by the reference)
#define BN    32          // batch
#define TN    512         // TFs
#define GN    2000        // genes
#define PPGN  10          // peaks per gene
#define PN    (GN*PPGN)   // 20000 peaks
#define EN    64000       // edges
#define NOUTN 10          // output channels
#define PQN   (PN/4)      // 5000 p-quads (float4 granules)

typedef float float4v __attribute__((ext_vector_type(4)));

// Stage 1: per_peak[b,p] = sum_t x[b,t,p] * W_sub[t,p]
// Traffic analysis (R3): at 6.3 TB/s, 441us total implies ~2.6GB of HBM
// traffic = x(1.31GB) + W_sub re-fetched per b-stream (32x41MB = 1.31GB).
// Fix: (a) 2 batches/thread -> W loaded once per 2 uses (halves demand
// structurally); (b) bg is the FAST blockIdx axis, so the 16 blocks sharing a
// W_sub ptile-column are dispatch-adjacent -> 2 blocks/XCD read it in lockstep
// -> per-XCD L2 serves the sliding t-window -> W_sub comes from HBM ~once.
// Grid 16x16 = 256 blocks x 320 threads = exactly 1 block/CU, no tail.
// x loads nontemporal (pure stream, keep caches for W_sub).
__global__ __launch_bounds__(320)
void k_perpeak(const float* __restrict__ x,
               const float* __restrict__ W_sub,
               float* __restrict__ per_peak) {
    int bg    = blockIdx.x;             // 0..15  (fast axis: b-group)
    int ptile = blockIdx.y;             // 0..15  (p-tile of 320 quads)
    int pq    = ptile * 320 + threadIdx.x;
    if (pq >= PQN) return;              // only last ptile is ragged
    int b0 = bg * 2;

    const float4v* xp0 = (const float4v*)(x + (size_t)b0 * TN * PN) + pq;
    const float4v* xp1 = xp0 + (size_t)TN * PQN;   // batch b0+1
    const float4v* wp  = (const float4v*)W_sub + pq;

    float4v acc0 = {0.f, 0.f, 0.f, 0.f};
    float4v acc1 = {0.f, 0.f, 0.f, 0.f};
#pragma unroll 8
    for (int t = 0; t < TN; ++t) {
        float4v wv  = wp[(size_t)t * PQN];
        float4v xv0 = __builtin_nontemporal_load(xp0 + (size_t)t * PQN);
        float4v xv1 = __builtin_nontemporal_load(xp1 + (size_t)t * PQN);
        acc0 = xv0 * wv + acc0;
        acc1 = xv1 * wv + acc1;
    }

    float4v* pp = (float4v*)(per_peak + (size_t)b0 * PN) + pq;
    *pp = acc0;
    *(pp + (size_t)PN / 4) = acc1;
}

// Stage 2: h[b,g] = relu(sum_{k<10} per_peak[b, g*10+k] + b_sub[g])
__global__ void k_h(const float* __restrict__ per_peak,
                    const float* __restrict__ b_sub,
                    float* __restrict__ h) {
    int idx = blockIdx.x * blockDim.x + threadIdx.x;
    if (idx >= BN * GN) return;
    int g = idx % GN, b = idx / GN;
    const float* pp = per_peak + (size_t)b * PN + g * PPGN;
    float s = b_sub[g];
#pragma unroll
    for (int k = 0; k < PPGN; ++k) s += pp[k];
    h[idx] = fmaxf(s, 0.0f);
}

// Stage 3a: degree of target nodes (col)
__global__ void k_deg(const int* __restrict__ col, float* __restrict__ deg) {
    int e = blockIdx.x * blockDim.x + threadIdx.x;
    if (e < EN) atomicAdd(&deg[col[e]], 1.0f);
}

// Stage 3b: dinv = deg^-1/2 (0 where deg == 0)
__global__ void k_dinv(const float* __restrict__ deg, float* __restrict__ dinv) {
    int g = blockIdx.x * blockDim.x + threadIdx.x;
    if (g < GN) {
        float d = deg[g];
        dinv[g] = (d > 0.0f) ? (1.0f / sqrtf(d)) : 0.0f;
    }
}

// Stage 3c: s[b,g] = sum_{e: col[e]==g} dinv[row]*dinv[col] * h[b,row]
// (GCNConv is rank-1 in the channel dim: agg[b,g,c] = W_gcn[c]*s[b,g] + b_gcn[c])
__global__ void k_s(const int* __restrict__ row, const int* __restrict__ col,
                    const float* __restrict__ dinv, const float* __restrict__ h,
                    float* __restrict__ s) {
    int idx = blockIdx.x * blockDim.x + threadIdx.x;
    if (idx >= EN * BN) return;
    int b = idx % BN;      // lanes share e -> broadcast row/col loads
    int e = idx / BN;
    int r = row[e], c = col[e];
    float nrm = dinv[r] * dinv[c];
    atomicAdd(&s[(size_t)b * GN + c], nrm * h[(size_t)b * GN + r]);
}

// Stage 4: out[b,n] = sum_g sum_c relu(W_gcn[c]*s[b,g]+b_gcn[c]) * W_out[n,2g+c] + b_out[n]
// One wave (64 threads) per (b,n).
__global__ void k_out(const float* __restrict__ s,
                      const float* __restrict__ W_gcn,
                      const float* __restrict__ b_gcn,
                      const float* __restrict__ W_out,
                      const float* __restrict__ b_out,
                      float* __restrict__ out) {
    int b = blockIdx.x / NOUTN;
    int n = blockIdx.x % NOUTN;
    int lane = threadIdx.x;

    float w0 = W_gcn[0], w1 = W_gcn[1];
    float c0 = b_gcn[0], c1 = b_gcn[1];

    float acc = 0.0f;
    for (int g = lane; g < GN; g += 64) {
        float sv = s[(size_t)b * GN + g];
        float g0 = fmaxf(fmaf(sv, w0, c0), 0.0f);
        float g1 = fmaxf(fmaf(sv, w1, c1), 0.0f);
        const float* wo = &W_out[(size_t)n * (GN * 2) + 2 * g];
        acc = fmaf(g0, wo[0], acc);
        acc = fmaf(g1, wo[1], acc);
    }
#pragma unroll
    for (int off = 32; off > 0; off >>= 1)
        acc += __shfl_down(acc, off);
    if (lane == 0) out[b * NOUTN + n] = acc + b_out[n];
}

extern "C" void kernel_launch(void* const* d_in, const int* in_sizes, int n_in,
                              void* d_out, int out_size, void* d_ws, size_t ws_size,
                              hipStream_t stream) {
    const float* x         = (const float*)d_in[0];
    const int*   edge_index= (const int*)  d_in[1];
    const float* W_sub     = (const float*)d_in[2];
    const float* b_sub     = (const float*)d_in[3];
    const float* W_gcn     = (const float*)d_in[4];
    const float* b_gcn     = (const float*)d_in[5];
    const float* W_out     = (const float*)d_in[6];
    const float* b_out     = (const float*)d_in[7];
    float* out = (float*)d_out;

    char* ws = (char*)d_ws;
    float* per_peak = (float*)(ws);                 // B*P   floats = 2,560,000 B
    float* h        = (float*)(ws + 2560000);       // B*G   floats =   256,000 B
    float* deg      = (float*)(ws + 2816000);       // G     floats =     8,000 B
    float* dinv     = (float*)(ws + 2824000);       // G     floats =     8,000 B
    float* s        = (float*)(ws + 2832000);       // B*G   floats =   256,000 B

    const int* row = edge_index;        // edge_index[0,:]
    const int* col = edge_index + EN;   // edge_index[1,:]

    // zero the atomic-accumulated buffers every call (graph-capture legal)
    hipMemsetAsync(deg, 0, GN * sizeof(float), stream);
    hipMemsetAsync(s,   0, (size_t)BN * GN * sizeof(float), stream);

    dim3 grid_pp(16, 16);   // x = b-group (fast), y = p-tile
    k_perpeak<<<grid_pp, 320, 0, stream>>>(x, W_sub, per_peak);
    k_h      <<<((BN * GN) + 255) / 256, 256, 0, stream>>>(per_peak, b_sub, h);
    k_deg    <<<(EN + 255) / 256,        256, 0, stream>>>(col, deg);
    k_dinv   <<<(GN + 255) / 256,        256, 0, stream>>>(deg, dinv);
    k_s      <<<((EN * BN) + 255) / 256, 256, 0, stream>>>(row, col, dinv, h, s);
    k_out    <<<BN * NOUTN, 64, 0, stream>>>(s, W_gcn, b_gcn, W_out, b_out, out);
}